// Round 4
// baseline (2205.459 us; speedup 1.0000x reference)
//
#include <hip/hip_runtime.h>
#include <cstdio>
#include <cstdint>

typedef _Float16 f16;
typedef f16 hf2   __attribute__((ext_vector_type(2)));
typedef f16 f16x8 __attribute__((ext_vector_type(8)));
typedef float f32x4 __attribute__((ext_vector_type(4)));
typedef unsigned int   u32;
typedef unsigned short u16;

#define B_    256
#define S_    512
#define IN_   32
#define H_    256
#define G3_   768
#define D_    32
#define PRED_ 96
#define TC_   32          // time-chunk
#define XPAD_ 776         // legacy fused path: padded xpc row (halves)
#define KPAD_ 72          // padded h quarter (halves): 64 data + 8 pad -> 144B stride

#if __has_builtin(__builtin_amdgcn_fdot2)
__device__ __forceinline__ float fdot2(hf2 a, hf2 b, float c) {
  return __builtin_amdgcn_fdot2(a, b, c, false);
}
#else
__device__ __forceinline__ float fdot2(hf2 a, hf2 b, float c) {
  return c + (float)a[0] * (float)b[0] + (float)a[1] * (float)b[1];
}
#endif

__device__ __forceinline__ float sigm(float x) {
  return __builtin_amdgcn_rcpf(1.f + __expf(-x));
}
__device__ __forceinline__ float tanh_fast(float x) {
  return 1.f - 2.f * __builtin_amdgcn_rcpf(__expf(2.f * x) + 1.f);
}
__device__ __forceinline__ hf2 bc2(u32 v) { return __builtin_bit_cast(hf2, v); }

__global__ void f32_to_f16_k(const float* __restrict__ in, f16* __restrict__ out, int n) {
  int i = blockIdx.x * blockDim.x + threadIdx.x;
  if (i < n) out[i] = (f16)in[i];
}

// biasc[n] = bih[n] + (n<512 ? bhh[n] : 0)  — r,z gate bhh folded into xp.
__global__ void make_bias(const float* __restrict__ bih, const float* __restrict__ bhh,
                          float* __restrict__ out) {
  int i = blockIdx.x * blockDim.x + threadIdx.x;
  if (i < G3_) out[i] = bih[i] + (i < 512 ? bhh[i] : 0.f);
}

__device__ __forceinline__ f16x8 cvt8(const float* p) {
  float4 lo = ((const float4*)p)[0];
  float4 hi = ((const float4*)p)[1];
  f16x8 r;
  r[0] = (f16)lo.x; r[1] = (f16)lo.y; r[2] = (f16)lo.z; r[3] = (f16)lo.w;
  r[4] = (f16)hi.x; r[5] = (f16)hi.y; r[6] = (f16)hi.z; r[7] = (f16)hi.w;
  return r;
}

// ---------------- standalone xp GEMM: xp = A @ Wih^T + biasc (f16 out) ------
// WG = 256 thr (4 waves), M-tile = 64 rows, full N = 768 (wave wv: 12 nt of 16).
// MFMA lives ONLY here (low reg demand ~55, AGPR behavior irrelevant).
template <int KK>   // 32: A = f32 x;  256: A = f16 h16
__global__ __launch_bounds__(256) void gemm_xp(
    const void* __restrict__ Asrc,
    const f16* __restrict__ Wih,     // f16 [768][KK]
    const float* __restrict__ biasc, // [768]
    u16* __restrict__ xp) {          // [131072][768] f16
  const int tid = threadIdx.x;
  const int wv = tid >> 6, lane = tid & 63, lm = lane & 15, q = lane >> 4;
  const size_t m0 = (size_t)blockIdx.x * 64;

#pragma unroll 1
  for (int nt = 0; nt < 12; ++nt) {
    const int n0 = wv * 192 + nt * 16;
    const f16* Bp = Wih + (size_t)(n0 + lm) * KK + q * 8;
    f32x4 acc[4];
#pragma unroll
    for (int j = 0; j < 4; ++j) acc[j] = f32x4{0.f, 0.f, 0.f, 0.f};
#pragma unroll
    for (int k0 = 0; k0 < KK; k0 += 32) {
      f16x8 bv = *(const f16x8*)(Bp + k0);
#pragma unroll
      for (int j = 0; j < 4; ++j) {
        f16x8 av;
        if constexpr (KK == 32) {
          av = cvt8((const float*)Asrc + (m0 + j * 16 + lm) * IN_ + k0 + q * 8);
        } else {
          av = *(const f16x8*)((const f16*)Asrc + (m0 + j * 16 + lm) * (size_t)H_ + k0 + q * 8);
        }
        acc[j] = __builtin_amdgcn_mfma_f32_16x16x32_f16(av, bv, acc[j], 0, 0, 0);
      }
    }
    const float bb = biasc[n0 + lm];
#pragma unroll
    for (int j = 0; j < 4; ++j)
#pragma unroll
      for (int r = 0; r < 4; ++r)   // D: col=lane&15, row=q*4+r
        xp[(m0 + j * 16 + q * 4 + r) * G3_ + n0 + lm] =
            __builtin_bit_cast(u16, (f16)(acc[j][r] + bb));
  }
}

// ---------------- pure-VALU recurrence kernel -------------------------------
// One WG (1024 thr) per batch row. Thread (p=tid>>2, kh=tid&3) owns rows
// {p, 256+p, 512+p} of W_hh, k-slice [kh*64, kh*64+64) -> w[24] uint4 = 96
// VGPRs of packed fp16, loaded ONCE (no MFMA in this kernel -> no AGPR split;
// LDS 116KB -> 1 WG/CU -> all heuristics agree on 4 waves/EU -> 128 VGPRs).
// Per chunk: stage 32 xp rows (48KB) global->LDS synchronously, then 32 steps
// with one barrier each. L0 h16 output staged in hhist, written coalesced
// once per chunk (no per-step global store drain at barriers).
template <int LAYER>
__global__ __attribute__((amdgpu_flat_work_group_size(1024, 1024)))
__attribute__((amdgpu_waves_per_eu(4, 4))) void gru_rec(
    const u16* __restrict__ xp,      // [B*S][768] f16 (bias folded for r,z)
    const f16* __restrict__ Whh16,   // f16 [768][256]
    const float* __restrict__ bhh,   // [768] (n-gate slice used)
    f16* __restrict__ h16_out,       // [B*S][256] (LAYER==0)
    float* __restrict__ hfinal) {    // [B][256]   (LAYER==1)
  const int b   = blockIdx.x;
  const int tid = threadIdx.x;
  const int p = tid >> 2, kh = tid & 3;

  // ---- W_hh -> registers (once): w[24] uint4 = 96 VGPRs ----
  uint4 w[24];
  const uint4* wsrc = (const uint4*)Whh16 + (size_t)p * 32 + kh * 8;
#pragma unroll
  for (int g = 0; g < 3; ++g)
#pragma unroll
    for (int u = 0; u < 8; ++u)
      w[g * 8 + u] = wsrc[g * 8192 + u];   // gate stride: 256 rows * 32 uint4
  const float bhn = bhh[512 + p];

  __shared__ u16 xbuf[2][TC_ * G3_];                 // 98,304 B
  __shared__ __align__(16) u16 hbuf[2][4 * KPAD_];   // 1,152 B
  __shared__ u16 hhist[TC_ * H_];                    // 16,384 B
  if (tid < 144) ((u32*)hbuf[0])[tid] = 0u;
  float h = 0.f;
  int cur = 0;
  const uint4* xsrc = (const uint4*)(xp + (size_t)b * S_ * G3_);

#pragma unroll 1
  for (int c = 0; c < S_ / TC_; ++c) {
    // ---- stage chunk c: 48KB = 3072 uint4, 3 per thread ----
    {
      const uint4* src = xsrc + (size_t)c * 3072;
      uint4 v0 = src[tid], v1 = src[1024 + tid], v2 = src[2048 + tid];
      uint4* dst = (uint4*)xbuf[c & 1];
      dst[tid] = v0; dst[1024 + tid] = v1; dst[2048 + tid] = v2;
    }
    __syncthreads();
    const u16* xrow0 = xbuf[c & 1];

#pragma unroll 1
    for (int tl = 0; tl < TC_; ++tl) {
      const uint4* hb = (const uint4*)((const u16*)hbuf[cur] + kh * KPAD_);
      float ar = 0.f, az = 0.f, an = 0.f;
#pragma unroll
      for (int cc = 0; cc < 8; ++cc) {
        uint4 hv = hb[cc];
        uint4 w0 = w[cc], w1 = w[8 + cc], w2 = w[16 + cc];
        ar = fdot2(bc2(w0.x), bc2(hv.x), ar);
        az = fdot2(bc2(w1.x), bc2(hv.x), az);
        an = fdot2(bc2(w2.x), bc2(hv.x), an);
        ar = fdot2(bc2(w0.y), bc2(hv.y), ar);
        az = fdot2(bc2(w1.y), bc2(hv.y), az);
        an = fdot2(bc2(w2.y), bc2(hv.y), an);
        ar = fdot2(bc2(w0.z), bc2(hv.z), ar);
        az = fdot2(bc2(w1.z), bc2(hv.z), az);
        an = fdot2(bc2(w2.z), bc2(hv.z), an);
        ar = fdot2(bc2(w0.w), bc2(hv.w), ar);
        az = fdot2(bc2(w1.w), bc2(hv.w), az);
        an = fdot2(bc2(w2.w), bc2(hv.w), an);
      }
      ar += __shfl_xor(ar, 1); ar += __shfl_xor(ar, 2);
      az += __shfl_xor(az, 1); az += __shfl_xor(az, 2);
      an += __shfl_xor(an, 1); an += __shfl_xor(an, 2);

      const u16* xrow = xrow0 + tl * G3_;
      float xr = (float)__builtin_bit_cast(f16, xrow[p]);
      float xz = (float)__builtin_bit_cast(f16, xrow[256 + p]);
      float xn = (float)__builtin_bit_cast(f16, xrow[512 + p]);
      float r = sigm(xr + ar);                 // bhh_r folded into xp
      float z = sigm(xz + az);                 // bhh_z folded into xp
      float n = tanh_fast(xn + r * (an + bhn));
      h = n + z * (h - n);

      if (kh == 0) {
        u16 h16v = __builtin_bit_cast(u16, (f16)h);
        hbuf[cur ^ 1][(p >> 6) * KPAD_ + (p & 63)] = h16v;
        if constexpr (LAYER == 0) hhist[tl * H_ + p] = h16v;
      }
      __syncthreads();   // step-t reads done AND step-t writes visible
      cur ^= 1;
    }

    if constexpr (LAYER == 0) {
      // coalesced chunk flush: 16KB, one uint4 per thread
      uint4 hv = ((const uint4*)hhist)[tid];
      ((uint4*)(h16_out + ((size_t)b * S_ + c * TC_) * H_))[tid] = hv;
      // next chunk's stage + __syncthreads orders these reads vs. rewrite
    }
  }
  if constexpr (LAYER == 1) {
    if (kh == 0) hfinal[b * H_ + p] = h;
  }
}

// ---------------- legacy fused kernel (fallback if ws too small) ------------
template <int LAYER>
__global__ __attribute__((amdgpu_flat_work_group_size(1024, 1024)))
__attribute__((amdgpu_waves_per_eu(4, 4))) void gru_fused_legacy(
    const void* __restrict__ Asrc, const f16* __restrict__ Wih,
    const float* __restrict__ bih, const f16* __restrict__ Whh16,
    const float* __restrict__ bhh, f16* __restrict__ h16_out,
    float* __restrict__ hfinal) {
  constexpr int KK = LAYER ? H_ : IN_;
  const int b   = blockIdx.x;
  const int tid = threadIdx.x;
  const int p  = tid >> 2, kh = tid & 3;
  const int wv = tid >> 6, lane = tid & 63, lm = lane & 15, q = lane >> 4;

  float bh[3];
#pragma unroll
  for (int g = 0; g < 3; g++) bh[g] = bhh[g * 256 + p];

  __shared__ u16 xpc[TC_ * XPAD_];
  __shared__ __align__(16) u16 hbuf[2][4 * KPAD_];
  if (tid < 144) ((u32*)hbuf[0])[tid] = 0u;
  float h = 0.f;
  f16* h16p = (LAYER == 0) ? (h16_out + (size_t)b * S_ * H_) : nullptr;
  int cur = 0;
  const uint4* wsrc = (const uint4*)Whh16 + (size_t)p * 32 + kh * 8;

  for (int c = 0; c < S_ / TC_; ++c) {
    const int t0 = c * TC_;
#pragma unroll 1
    for (int nt = 0; nt < 3; ++nt) {
      const int n0 = wv * 48 + nt * 16;
      const f16* Bp = Wih + (size_t)(n0 + lm) * KK + q * 8;
      f32x4 ac0 = {0.f, 0.f, 0.f, 0.f}, ac1 = ac0;
#pragma unroll
      for (int k0 = 0; k0 < KK; k0 += 32) {
        f16x8 bv = *(const f16x8*)(Bp + k0);
        f16x8 a0, a1;
        if constexpr (LAYER == 0) {
          const float* xr = (const float*)Asrc + ((size_t)b * S_ + t0 + lm) * IN_ + k0 + q * 8;
          a0 = cvt8(xr);
          a1 = cvt8(xr + 16 * IN_);
        } else {
          const f16* ar = (const f16*)Asrc + ((size_t)b * S_ + t0 + lm) * H_ + k0 + q * 8;
          a0 = *(const f16x8*)ar;
          a1 = *(const f16x8*)(ar + 16 * H_);
        }
        ac0 = __builtin_amdgcn_mfma_f32_16x16x32_f16(a0, bv, ac0, 0, 0, 0);
        ac1 = __builtin_amdgcn_mfma_f32_16x16x32_f16(a1, bv, ac1, 0, 0, 0);
      }
      const float bb = bih[n0 + lm];
#pragma unroll
      for (int r = 0; r < 4; ++r) {
        xpc[(q * 4 + r) * XPAD_ + n0 + lm]      = __builtin_bit_cast(u16, (f16)(ac0[r] + bb));
        xpc[(16 + q * 4 + r) * XPAD_ + n0 + lm] = __builtin_bit_cast(u16, (f16)(ac1[r] + bb));
      }
    }
    uint4 wraw[24];
#pragma unroll
    for (int g = 0; g < 3; ++g)
#pragma unroll
      for (int u = 0; u < 8; ++u)
        wraw[g * 8 + u] = wsrc[g * 8192 + u];
    __syncthreads();

    for (int tl = 0; tl < TC_; ++tl) {
      float ar = 0.f, az = 0.f, an = 0.f;
      const uint4* hb = (const uint4*)((const u16*)hbuf[cur] + kh * KPAD_);
#pragma unroll
      for (int cc = 0; cc < 8; ++cc) {
        uint4 hv = hb[cc];
        uint4 w0 = wraw[cc], w1 = wraw[8 + cc], w2 = wraw[16 + cc];
        ar = fdot2(bc2(w0.x), bc2(hv.x), ar);
        az = fdot2(bc2(w1.x), bc2(hv.x), az);
        an = fdot2(bc2(w2.x), bc2(hv.x), an);
        ar = fdot2(bc2(w0.y), bc2(hv.y), ar);
        az = fdot2(bc2(w1.y), bc2(hv.y), az);
        an = fdot2(bc2(w2.y), bc2(hv.y), an);
        ar = fdot2(bc2(w0.z), bc2(hv.z), ar);
        az = fdot2(bc2(w1.z), bc2(hv.z), az);
        an = fdot2(bc2(w2.z), bc2(hv.z), an);
        ar = fdot2(bc2(w0.w), bc2(hv.w), ar);
        az = fdot2(bc2(w1.w), bc2(hv.w), az);
        an = fdot2(bc2(w2.w), bc2(hv.w), an);
      }
      ar += __shfl_xor(ar, 1); ar += __shfl_xor(ar, 2);
      az += __shfl_xor(az, 1); az += __shfl_xor(az, 2);
      an += __shfl_xor(an, 1); an += __shfl_xor(an, 2);

      const u16* xrow = xpc + tl * XPAD_;
      float xr = (float)__builtin_bit_cast(f16, xrow[p]);
      float xz = (float)__builtin_bit_cast(f16, xrow[256 + p]);
      float xn = (float)__builtin_bit_cast(f16, xrow[512 + p]);
      float r = sigm(xr + ar + bh[0]);
      float z = sigm(xz + az + bh[1]);
      float n = tanh_fast(xn + r * (an + bh[2]));
      h = (1.f - z) * n + z * h;

      if (kh == 0) {
        hbuf[cur ^ 1][(p >> 6) * KPAD_ + (p & 63)] = __builtin_bit_cast(u16, (f16)h);
        if constexpr (LAYER == 0) h16p[(size_t)(t0 + tl) * H_ + p] = (f16)h;
      }
      __syncthreads();
      cur ^= 1;
    }
  }
  if constexpr (LAYER == 1) {
    if (kh == 0) hfinal[b * H_ + p] = h;
  }
}

// ---------------- projection + 96-step rollout ------------------------------
__global__ __launch_bounds__(128) void proj_rollout(
    const float* __restrict__ hfinal, const float* __restrict__ Wp,
    const float* __restrict__ bp, const float* __restrict__ Cm,
    const float* __restrict__ rld, const float* __restrict__ rtd,
    const float* __restrict__ rg, const float* __restrict__ om,
    float* __restrict__ out) {
  const int b = blockIdx.x, tid = threadIdx.x;
  __shared__ float fh[256];
  __shared__ float sb[128];
  ((float2*)fh)[tid] = ((const float2*)(hfinal + b * 256))[tid];
  __syncthreads();
  const float4* wrow = (const float4*)(Wp + tid * 256);
  float acc = 0.f;
#pragma unroll 16
  for (int k4 = 0; k4 < 64; k4++) {
    float4 wv = wrow[k4];
    acc += wv.x * fh[4 * k4] + wv.y * fh[4 * k4 + 1] + wv.z * fh[4 * k4 + 2] +
           wv.w * fh[4 * k4 + 3];
  }
  sb[tid] = acc + bp[tid];
  __syncthreads();
  if (tid < 32) {
    const int dd = tid;
    float s0 = sb[dd * 4], s1 = sb[dd * 4 + 1], s2 = sb[dd * 4 + 2], s3 = sb[dd * 4 + 3];
    float al = sigm(rld[dd]) * 0.15f + 0.85f;
    float at = sigm(rtd[dd]) * 0.25f + 0.70f;
    float g  = sigm(rg[dd]) * 0.20f + 0.80f;
    float cw = cosf(om[dd]), sw = sinf(om[dd]);
    float r00 = g * cw, r01 = -g * sw, r10 = g * sw, r11 = g * cw;
    float c0 = Cm[dd * 4], c1 = Cm[dd * 4 + 1], c2 = Cm[dd * 4 + 2], c3 = Cm[dd * 4 + 3];
    float* op = out + (size_t)b * PRED_ * D_ + dd;
    for (int t = 0; t < PRED_; t++) {
      float n0 = s0 * al, n1 = s1 * at;
      float n2 = s2 * r00 + s3 * r10;
      float n3 = s2 * r01 + s3 * r11;
      op[(size_t)t * D_] = c0 * n0 + c1 * n1 + c2 * n2 + c3 * n3;
      s0 = n0; s1 = n1; s2 = n2; s3 = n3;
    }
  }
}

extern "C" void kernel_launch(void* const* d_in, const int* in_sizes, int n_in,
                              void* d_out, int out_size, void* d_ws,
                              size_t ws_size, hipStream_t stream) {
  (void)in_sizes; (void)n_in; (void)out_size;
  const float* x     = (const float*)d_in[0];
  const float* Wih0  = (const float*)d_in[1];
  const float* Whh0  = (const float*)d_in[2];
  const float* bih0  = (const float*)d_in[3];
  const float* bhh0  = (const float*)d_in[4];
  const float* Wih1  = (const float*)d_in[5];
  const float* Whh1  = (const float*)d_in[6];
  const float* bih1  = (const float*)d_in[7];
  const float* bhh1  = (const float*)d_in[8];
  const float* Wproj = (const float*)d_in[9];
  const float* bproj = (const float*)d_in[10];
  const float* Cm    = (const float*)d_in[11];
  const float* rld   = (const float*)d_in[12];
  const float* rtd   = (const float*)d_in[13];
  const float* rg    = (const float*)d_in[14];
  const float* om    = (const float*)d_in[15];
  float* out = (float*)d_out;

  char* ws = (char*)d_ws;
  // Plan A layout
  const size_t wi0_off  = 0;           //    49,152
  const size_t wi1_off  = 49152;       //   393,216
  const size_t whh0_off = 442368;      //   393,216
  const size_t whh1_off = 835584;      //   393,216
  const size_t b0_off   = 1228800;     //     3,072
  const size_t b1_off   = 1231872;     //     3,072
  const size_t h16_off  = 1234944;     // 67,108,864
  const size_t xp_off   = 68343808;    // 201,326,592
  const size_t needA    = 269670400;
  // Legacy layout
  const size_t l_h16_off = 442368;
  const size_t l_hf_off  = 67551232;
  const size_t needL     = 67813376;

  if (ws_size >= needA) {
    f16* wi016  = (f16*)(ws + wi0_off);
    f16* wi116  = (f16*)(ws + wi1_off);
    f16* whh016 = (f16*)(ws + whh0_off);
    f16* whh116 = (f16*)(ws + whh1_off);
    float* bias0 = (float*)(ws + b0_off);
    float* bias1 = (float*)(ws + b1_off);
    f16* h16    = (f16*)(ws + h16_off);
    u16* xp     = (u16*)(ws + xp_off);
    // hfinal parked in d_out scratch (262,144 B of the 3.1 MB out buffer);
    // consumed by proj_rollout before it overwrites out.
    float* hfin = (float*)d_out;

    f32_to_f16_k<<<96, 256, 0, stream>>>(Wih0, wi016, G3_ * IN_);
    f32_to_f16_k<<<768, 256, 0, stream>>>(Wih1, wi116, G3_ * H_);
    f32_to_f16_k<<<768, 256, 0, stream>>>(Whh0, whh016, G3_ * H_);
    f32_to_f16_k<<<768, 256, 0, stream>>>(Whh1, whh116, G3_ * H_);
    make_bias<<<3, 256, 0, stream>>>(bih0, bhh0, bias0);
    make_bias<<<3, 256, 0, stream>>>(bih1, bhh1, bias1);

    gemm_xp<IN_><<<B_ * S_ / 64, 256, 0, stream>>>((const void*)x, wi016, bias0, xp);
    gru_rec<0><<<B_, 1024, 0, stream>>>(xp, whh016, bhh0, h16, nullptr);
    gemm_xp<H_><<<B_ * S_ / 64, 256, 0, stream>>>((const void*)h16, wi116, bias1, xp);
    gru_rec<1><<<B_, 1024, 0, stream>>>(xp, whh116, bhh1, nullptr, hfin);
    proj_rollout<<<B_, 128, 0, stream>>>(hfin, Wproj, bproj, Cm, rld, rtd, rg, om, out);
  } else if (ws_size >= needL) {
    f16* wi016  = (f16*)(ws + wi0_off);
    f16* wi116  = (f16*)(ws + wi1_off);
    f16* h16    = (f16*)(ws + l_h16_off);
    float* hfin = (float*)(ws + l_hf_off);
    f16* whh016 = (f16*)d_out;
    f16* whh116 = (f16*)d_out + (size_t)G3_ * H_;

    f32_to_f16_k<<<96, 256, 0, stream>>>(Wih0, wi016, G3_ * IN_);
    f32_to_f16_k<<<768, 256, 0, stream>>>(Wih1, wi116, G3_ * H_);
    f32_to_f16_k<<<768, 256, 0, stream>>>(Whh0, whh016, G3_ * H_);
    f32_to_f16_k<<<768, 256, 0, stream>>>(Whh1, whh116, G3_ * H_);
    gru_fused_legacy<0><<<B_, 1024, 0, stream>>>((const void*)x,   wi016, bih0, whh016, bhh0, h16, nullptr);
    gru_fused_legacy<1><<<B_, 1024, 0, stream>>>((const void*)h16, wi116, bih1, whh116, bhh1, nullptr, hfin);
    proj_rollout<<<B_, 128, 0, stream>>>(hfin, Wproj, bproj, Cm, rld, rtd, rg, om, out);
  } else {
    fprintf(stderr, "kernel_launch: ws too small: have %zu need %zu — skipping\n",
            ws_size, needL);
  }
}

// Round 5
// 1687.350 us; speedup vs baseline: 1.3071x; 1.3071x over previous
//
#include <hip/hip_runtime.h>
#include <cstdio>
#include <cstdint>

typedef _Float16 f16;
typedef f16 hf2   __attribute__((ext_vector_type(2)));
typedef f16 f16x8 __attribute__((ext_vector_type(8)));
typedef float f32x4 __attribute__((ext_vector_type(4)));
typedef unsigned int   u32;
typedef unsigned short u16;

#define B_    256
#define S_    512
#define IN_   32
#define H_    256
#define G3_   768
#define D_    32
#define PRED_ 96
#define TC_   32          // in-kernel time sub-chunk (steps per LDS stage)
#define KPAD_ 72          // padded h quarter (halves): 64 data + 8 pad -> 144B stride

#if __has_builtin(__builtin_amdgcn_fdot2)
__device__ __forceinline__ float fdot2(hf2 a, hf2 b, float c) {
  return __builtin_amdgcn_fdot2(a, b, c, false);
}
#else
__device__ __forceinline__ float fdot2(hf2 a, hf2 b, float c) {
  return c + (float)a[0] * (float)b[0] + (float)a[1] * (float)b[1];
}
#endif

__device__ __forceinline__ float sigm(float x) {
  return __builtin_amdgcn_rcpf(1.f + __expf(-x));
}
__device__ __forceinline__ float tanh_fast(float x) {
  return 1.f - 2.f * __builtin_amdgcn_rcpf(__expf(2.f * x) + 1.f);
}
__device__ __forceinline__ hf2 bc2(u32 v) { return __builtin_bit_cast(hf2, v); }

__global__ void f32_to_f16_k(const float* __restrict__ in, f16* __restrict__ out, int n) {
  int i = blockIdx.x * blockDim.x + threadIdx.x;
  if (i < n) out[i] = (f16)in[i];
}

// biasc[n] = bih[n] + (n<512 ? bhh[n] : 0)  — r,z gate bhh folded into xp.
__global__ void make_bias(const float* __restrict__ bih, const float* __restrict__ bhh,
                          float* __restrict__ out) {
  int i = blockIdx.x * blockDim.x + threadIdx.x;
  if (i < G3_) out[i] = bih[i] + (i < 512 ? bhh[i] : 0.f);
}

__device__ __forceinline__ f16x8 cvt8(const float* p) {
  float4 lo = ((const float4*)p)[0];
  float4 hi = ((const float4*)p)[1];
  f16x8 r;
  r[0] = (f16)lo.x; r[1] = (f16)lo.y; r[2] = (f16)lo.z; r[3] = (f16)lo.w;
  r[4] = (f16)hi.x; r[5] = (f16)hi.y; r[6] = (f16)hi.z; r[7] = (f16)hi.w;
  return r;
}

// ------- chunked xp GEMM: xp_chunk = A_chunk @ Wih^T + biasc (f16 out) ------
// WG = 256 thr (4 waves). Each block computes a 64-row x 768-col tile.
// Block bid covers batch b = bid/tiles_pb, sub-tile hf = bid%tiles_pb where
// tiles_pb = tl_rows/64. A element offset: b*aBlk + (hf*64+row)*KK.
// Output rows are chunk-local: (b*tl_rows + hf*64 + row)*768.
// MFMA lives ONLY here (reg demand ~60; the 1024-thr VGPR cap is irrelevant).
template <int KK>   // 32: A = f32 x;  256: A = f16 (h1 chunk)
__global__ __launch_bounds__(256) void gemm_xp(
    const void* __restrict__ Asrc, size_t aBlk, int tl_rows,
    const f16* __restrict__ Wih,     // f16 [768][KK]
    const float* __restrict__ biasc, // [768]
    u16* __restrict__ xp) {          // chunk-local [B*tl_rows][768] f16
  const int tid = threadIdx.x;
  const int wv = tid >> 6, lane = tid & 63, lm = lane & 15, q = lane >> 4;
  const int tiles_pb = tl_rows >> 6;
  const int b = blockIdx.x / tiles_pb, hf = blockIdx.x % tiles_pb;
  const size_t arow0 = (size_t)b * aBlk + (size_t)(hf * 64) * KK;
  const size_t orow0 = (size_t)b * tl_rows + hf * 64;

#pragma unroll 1
  for (int nt = 0; nt < 12; ++nt) {
    const int n0 = wv * 192 + nt * 16;
    const f16* Bp = Wih + (size_t)(n0 + lm) * KK + q * 8;
    f32x4 acc[4];
#pragma unroll
    for (int j = 0; j < 4; ++j) acc[j] = f32x4{0.f, 0.f, 0.f, 0.f};
#pragma unroll
    for (int k0 = 0; k0 < KK; k0 += 32) {
      f16x8 bv = *(const f16x8*)(Bp + k0);
#pragma unroll
      for (int j = 0; j < 4; ++j) {
        f16x8 av;
        if constexpr (KK == 32) {
          av = cvt8((const float*)Asrc + arow0 + (size_t)(j * 16 + lm) * KK + k0 + q * 8);
        } else {
          av = *(const f16x8*)((const f16*)Asrc + arow0 + (size_t)(j * 16 + lm) * KK + k0 + q * 8);
        }
        acc[j] = __builtin_amdgcn_mfma_f32_16x16x32_f16(av, bv, acc[j], 0, 0, 0);
      }
    }
    const float bb = biasc[n0 + lm];
#pragma unroll
    for (int j = 0; j < 4; ++j)
#pragma unroll
      for (int r = 0; r < 4; ++r)   // D: col=lane&15 (n), row=q*4+r (m)
        xp[(orow0 + j * 16 + q * 4 + r) * G3_ + n0 + lm] =
            __builtin_bit_cast(u16, (f16)(acc[j][r] + bb));
  }
}

// ---------------- pure-VALU recurrence kernel (chunked) ---------------------
// One WG (1024 thr) per batch row; processes tl_rows steps, continuing from
// f32 hstate. Thread (p=tid>>2, kh=tid&3) owns W_hh rows {p,256+p,512+p},
// k-slice [kh*64, kh*64+64) -> w[24] uint4 = 96 VGPRs of packed fp16, loaded
// once. No MFMA -> no AGPR reservation; LDS 116KB -> 1 WG/CU -> heuristics
// agree on 4 waves/EU -> 128 arch VGPRs (round-1/2 lesson: MFMA kernels get
// capped at 64 and spill). Per TC_=32 sub-chunk: stage 48KB xp -> LDS, then
// 32 steps with one barrier each (double-buffered fp16 h in LDS, padded
// quarters -> conflict-free broadcast reads).
template <int LAYER>
__global__ __attribute__((amdgpu_flat_work_group_size(1024, 1024)))
__attribute__((amdgpu_waves_per_eu(4, 4))) void gru_rec(
    const u16* __restrict__ xp,      // chunk-local [B*tl_rows][768] f16
    const f16* __restrict__ Whh16,   // f16 [768][256]
    const float* __restrict__ bhh,   // [768] (n-gate slice used)
    float* __restrict__ hstate,      // f32 [B][256], in+out across chunks
    f16* __restrict__ h1c,           // chunk-local [B*tl_rows][256] (LAYER==0)
    int tl_rows, int first) {
  const int b   = blockIdx.x;
  const int tid = threadIdx.x;
  const int p = tid >> 2, kh = tid & 3;

  // ---- W_hh -> registers (once): w[24] uint4 = 96 VGPRs ----
  uint4 w[24];
  const uint4* wsrc = (const uint4*)Whh16 + (size_t)p * 32 + kh * 8;
#pragma unroll
  for (int g = 0; g < 3; ++g)
#pragma unroll
    for (int u = 0; u < 8; ++u)
      w[g * 8 + u] = wsrc[g * 8192 + u];   // gate stride: 256 rows * 32 uint4
  const float bhn = bhh[512 + p];

  __shared__ u16 xbuf[2][TC_ * G3_];                 // 98,304 B
  __shared__ __align__(16) u16 hbuf[2][4 * KPAD_];   // 1,152 B
  __shared__ u16 hhist[TC_ * H_];                    // 16,384 B

  float h = first ? 0.f : hstate[b * H_ + p];
  if (kh == 0)
    hbuf[0][(p >> 6) * KPAD_ + (p & 63)] = __builtin_bit_cast(u16, (f16)h);
  int cur = 0;
  const uint4* xsrc = (const uint4*)xp + (size_t)b * tl_rows * 96;  // 96 uint4/row
  const int nsub = tl_rows >> 5;

#pragma unroll 1
  for (int c2 = 0; c2 < nsub; ++c2) {
    // ---- stage sub-chunk: 48KB = 3072 uint4, 3 per thread ----
    {
      const uint4* src = xsrc + (size_t)c2 * 3072;
      uint4 v0 = src[tid], v1 = src[1024 + tid], v2 = src[2048 + tid];
      uint4* dst = (uint4*)xbuf[c2 & 1];
      dst[tid] = v0; dst[1024 + tid] = v1; dst[2048 + tid] = v2;
    }
    __syncthreads();   // also covers hbuf[0] init before the first step
    const u16* xrow0 = xbuf[c2 & 1];

#pragma unroll 1
    for (int tl = 0; tl < TC_; ++tl) {
      const uint4* hb = (const uint4*)((const u16*)hbuf[cur] + kh * KPAD_);
      float ar = 0.f, az = 0.f, an = 0.f;
#pragma unroll
      for (int cc = 0; cc < 8; ++cc) {
        uint4 hv = hb[cc];
        uint4 w0 = w[cc], w1 = w[8 + cc], w2 = w[16 + cc];
        ar = fdot2(bc2(w0.x), bc2(hv.x), ar);
        az = fdot2(bc2(w1.x), bc2(hv.x), az);
        an = fdot2(bc2(w2.x), bc2(hv.x), an);
        ar = fdot2(bc2(w0.y), bc2(hv.y), ar);
        az = fdot2(bc2(w1.y), bc2(hv.y), az);
        an = fdot2(bc2(w2.y), bc2(hv.y), an);
        ar = fdot2(bc2(w0.z), bc2(hv.z), ar);
        az = fdot2(bc2(w1.z), bc2(hv.z), az);
        an = fdot2(bc2(w2.z), bc2(hv.z), an);
        ar = fdot2(bc2(w0.w), bc2(hv.w), ar);
        az = fdot2(bc2(w1.w), bc2(hv.w), az);
        an = fdot2(bc2(w2.w), bc2(hv.w), an);
      }
      ar += __shfl_xor(ar, 1); ar += __shfl_xor(ar, 2);
      az += __shfl_xor(az, 1); az += __shfl_xor(az, 2);
      an += __shfl_xor(an, 1); an += __shfl_xor(an, 2);

      const u16* xrow = xrow0 + tl * G3_;
      float xr = (float)__builtin_bit_cast(f16, xrow[p]);
      float xz = (float)__builtin_bit_cast(f16, xrow[256 + p]);
      float xn = (float)__builtin_bit_cast(f16, xrow[512 + p]);
      float r = sigm(xr + ar);                 // bhh_r folded into xp
      float z = sigm(xz + az);                 // bhh_z folded into xp
      float n = tanh_fast(xn + r * (an + bhn));
      h = n + z * (h - n);

      if (kh == 0) {
        u16 h16v = __builtin_bit_cast(u16, (f16)h);
        hbuf[cur ^ 1][(p >> 6) * KPAD_ + (p & 63)] = h16v;
        if constexpr (LAYER == 0) hhist[tl * H_ + p] = h16v;
      }
      __syncthreads();   // step-t reads done AND step-t writes visible
      cur ^= 1;
    }

    if constexpr (LAYER == 0) {
      // coalesced sub-chunk flush: 16KB, one uint4 per thread.
      // (next stage's __syncthreads orders these reads vs. hhist rewrite)
      uint4 hv = ((const uint4*)hhist)[tid];
      ((uint4*)(h1c + ((size_t)b * tl_rows + c2 * TC_) * H_))[tid] = hv;
    }
  }
  if (kh == 0) hstate[b * H_ + p] = h;
}

// ---------------- projection + 96-step rollout ------------------------------
__global__ __launch_bounds__(128) void proj_rollout(
    const float* __restrict__ hfinal, const float* __restrict__ Wp,
    const float* __restrict__ bp, const float* __restrict__ Cm,
    const float* __restrict__ rld, const float* __restrict__ rtd,
    const float* __restrict__ rg, const float* __restrict__ om,
    float* __restrict__ out) {
  const int b = blockIdx.x, tid = threadIdx.x;
  __shared__ float fh[256];
  __shared__ float sb[128];
  ((float2*)fh)[tid] = ((const float2*)(hfinal + b * 256))[tid];
  __syncthreads();
  const float4* wrow = (const float4*)(Wp + tid * 256);
  float acc = 0.f;
#pragma unroll 16
  for (int k4 = 0; k4 < 64; k4++) {
    float4 wv = wrow[k4];
    acc += wv.x * fh[4 * k4] + wv.y * fh[4 * k4 + 1] + wv.z * fh[4 * k4 + 2] +
           wv.w * fh[4 * k4 + 3];
  }
  sb[tid] = acc + bp[tid];
  __syncthreads();
  if (tid < 32) {
    const int dd = tid;
    float s0 = sb[dd * 4], s1 = sb[dd * 4 + 1], s2 = sb[dd * 4 + 2], s3 = sb[dd * 4 + 3];
    float al = sigm(rld[dd]) * 0.15f + 0.85f;
    float at = sigm(rtd[dd]) * 0.25f + 0.70f;
    float g  = sigm(rg[dd]) * 0.20f + 0.80f;
    float cw = cosf(om[dd]), sw = sinf(om[dd]);
    float r00 = g * cw, r01 = -g * sw, r10 = g * sw, r11 = g * cw;
    float c0 = Cm[dd * 4], c1 = Cm[dd * 4 + 1], c2 = Cm[dd * 4 + 2], c3 = Cm[dd * 4 + 3];
    float* op = out + (size_t)b * PRED_ * D_ + dd;
    for (int t = 0; t < PRED_; t++) {
      float n0 = s0 * al, n1 = s1 * at;
      float n2 = s2 * r00 + s3 * r10;
      float n3 = s2 * r01 + s3 * r11;
      op[(size_t)t * D_] = c0 * n0 + c1 * n1 + c2 * n2 + c3 * n3;
      s0 = n0; s1 = n1; s2 = n2; s3 = n3;
    }
  }
}

extern "C" void kernel_launch(void* const* d_in, const int* in_sizes, int n_in,
                              void* d_out, int out_size, void* d_ws,
                              size_t ws_size, hipStream_t stream) {
  (void)in_sizes; (void)n_in; (void)out_size;
  const float* x     = (const float*)d_in[0];
  const float* Wih0  = (const float*)d_in[1];
  const float* Whh0  = (const float*)d_in[2];
  const float* bih0  = (const float*)d_in[3];
  const float* bhh0  = (const float*)d_in[4];
  const float* Wih1  = (const float*)d_in[5];
  const float* Whh1  = (const float*)d_in[6];
  const float* bih1  = (const float*)d_in[7];
  const float* bhh1  = (const float*)d_in[8];
  const float* Wproj = (const float*)d_in[9];
  const float* bproj = (const float*)d_in[10];
  const float* Cm    = (const float*)d_in[11];
  const float* rld   = (const float*)d_in[12];
  const float* rtd   = (const float*)d_in[13];
  const float* rg    = (const float*)d_in[14];
  const float* om    = (const float*)d_in[15];
  float* out = (float*)d_out;

  char* ws = (char*)d_ws;
  // fixed region
  const size_t wi0_off  = 0;           //    49,152
  const size_t wi1_off  = 49152;       //   393,216
  const size_t whh0_off = 442368;      //   393,216
  const size_t whh1_off = 835584;      //   393,216
  const size_t b0_off   = 1228800;     //     3,072
  const size_t b1_off   = 1231872;     //     3,072
  const size_t hs0_off  = 1234944;     //   262,144 (f32 [B][256])
  const size_t hs1_off  = 1497088;     //   262,144
  const size_t h1c_off  = 1759232;     // h1 chunk: B*TL*256*2
  // xpc follows h1c; sizes depend on TL.
  const size_t need64  = h1c_off + (size_t)B_ * 64 * H_ * 2  + (size_t)B_ * 64 * G3_ * 2;   // 35,313,664
  const size_t need128 = h1c_off + (size_t)B_ * 128 * H_ * 2 + (size_t)B_ * 128 * G3_ * 2;  // 68,868,096

  if (ws_size < need64) {
    fprintf(stderr, "kernel_launch: ws too small: have %zu need %zu — skipping\n",
            ws_size, need64);
    return;
  }
  const int TL = (ws_size >= need128) ? 128 : 64;
  const size_t xpc_off = h1c_off + (size_t)B_ * TL * H_ * 2;

  f16* wi016   = (f16*)(ws + wi0_off);
  f16* wi116   = (f16*)(ws + wi1_off);
  f16* whh016  = (f16*)(ws + whh0_off);
  f16* whh116  = (f16*)(ws + whh1_off);
  float* bias0 = (float*)(ws + b0_off);
  float* bias1 = (float*)(ws + b1_off);
  float* hst0  = (float*)(ws + hs0_off);
  float* hst1  = (float*)(ws + hs1_off);
  f16* h1c     = (f16*)(ws + h1c_off);
  u16* xpc     = (u16*)(ws + xpc_off);

  f32_to_f16_k<<<96, 256, 0, stream>>>(Wih0, wi016, G3_ * IN_);
  f32_to_f16_k<<<768, 256, 0, stream>>>(Wih1, wi116, G3_ * H_);
  f32_to_f16_k<<<768, 256, 0, stream>>>(Whh0, whh016, G3_ * H_);
  f32_to_f16_k<<<768, 256, 0, stream>>>(Whh1, whh116, G3_ * H_);
  make_bias<<<3, 256, 0, stream>>>(bih0, bhh0, bias0);
  make_bias<<<3, 256, 0, stream>>>(bih1, bhh1, bias1);

  const int nchunks = S_ / TL;
  const int gblocks = B_ * (TL / 64);
  for (int c = 0; c < nchunks; ++c) {
    gemm_xp<IN_><<<gblocks, 256, 0, stream>>>(
        (const void*)(x + (size_t)c * TL * IN_), (size_t)S_ * IN_, TL, wi016, bias0, xpc);
    gru_rec<0><<<B_, 1024, 0, stream>>>(xpc, whh016, bhh0, hst0, h1c, TL, c == 0);
    gemm_xp<H_><<<gblocks, 256, 0, stream>>>(
        (const void*)h1c, (size_t)TL * H_, TL, wi116, bias1, xpc);
    gru_rec<1><<<B_, 1024, 0, stream>>>(xpc, whh116, bhh1, hst1, nullptr, TL, c == 0);
  }
  proj_rollout<<<B_, 128, 0, stream>>>(hst1, Wproj, bproj, Cm, rld, rtd, rg, om, out);
}

// Round 7
// 1555.442 us; speedup vs baseline: 1.4179x; 1.0848x over previous
//
#include <hip/hip_runtime.h>
#include <cstdio>
#include <cstdint>

typedef _Float16 f16;
typedef f16 hf2   __attribute__((ext_vector_type(2)));
typedef f16 f16x8 __attribute__((ext_vector_type(8)));
typedef float f32x4 __attribute__((ext_vector_type(4)));
typedef unsigned int   u32;
typedef unsigned short u16;

#define B_    256
#define S_    512
#define IN_   32
#define H_    256
#define G3_   768
#define D_    32
#define PRED_ 96
#define TC_   32          // in-kernel time sub-chunk (steps per LDS stage)

#if __has_builtin(__builtin_amdgcn_fdot2)
__device__ __forceinline__ float fdot2(hf2 a, hf2 b, float c) {
  return __builtin_amdgcn_fdot2(a, b, c, false);
}
#else
__device__ __forceinline__ float fdot2(hf2 a, hf2 b, float c) {
  return c + (float)a[0] * (float)b[0] + (float)a[1] * (float)b[1];
}
#endif

__device__ __forceinline__ float sigm(float x) {
  return __builtin_amdgcn_rcpf(1.f + __expf(-x));
}
__device__ __forceinline__ float tanh_fast(float x) {
  return 1.f - 2.f * __builtin_amdgcn_rcpf(__expf(2.f * x) + 1.f);
}
__device__ __forceinline__ hf2 bc2(u32 v) { return __builtin_bit_cast(hf2, v); }

__global__ void f32_to_f16_k(const float* __restrict__ in, f16* __restrict__ out, int n) {
  int i = blockIdx.x * blockDim.x + threadIdx.x;
  if (i < n) out[i] = (f16)in[i];
}

// biasc[n] = bih[n] + (n<512 ? bhh[n] : 0)  — r,z gate bhh folded into xp.
__global__ void make_bias(const float* __restrict__ bih, const float* __restrict__ bhh,
                          float* __restrict__ out) {
  int i = blockIdx.x * blockDim.x + threadIdx.x;
  if (i < G3_) out[i] = bih[i] + (i < 512 ? bhh[i] : 0.f);
}

__device__ __forceinline__ f16x8 cvt8(const float* p) {
  float4 lo = ((const float4*)p)[0];
  float4 hi = ((const float4*)p)[1];
  f16x8 r;
  r[0] = (f16)lo.x; r[1] = (f16)lo.y; r[2] = (f16)lo.z; r[3] = (f16)lo.w;
  r[4] = (f16)hi.x; r[5] = (f16)hi.y; r[6] = (f16)hi.z; r[7] = (f16)hi.w;
  return r;
}

// ------- chunked xp GEMM: xp_chunk = A_chunk @ Wih^T + biasc (f16 out) ------
// WG = 256 thr (4 waves). Each block computes a 64-row x 768-col tile.
template <int KK>   // 32: A = f32 x;  256: A = f16 (h1 chunk)
__global__ __launch_bounds__(256) void gemm_xp(
    const void* __restrict__ Asrc, size_t aBlk, int tl_rows,
    const f16* __restrict__ Wih,     // f16 [768][KK]
    const float* __restrict__ biasc, // [768]
    u16* __restrict__ xp) {          // chunk-local [B*tl_rows][768] f16
  const int tid = threadIdx.x;
  const int wv = tid >> 6, lane = tid & 63, lm = lane & 15, q = lane >> 4;
  const int tiles_pb = tl_rows >> 6;
  const int b = blockIdx.x / tiles_pb, hf = blockIdx.x % tiles_pb;
  const size_t arow0 = (size_t)b * aBlk + (size_t)(hf * 64) * KK;
  const size_t orow0 = (size_t)b * tl_rows + hf * 64;

#pragma unroll 1
  for (int nt = 0; nt < 12; ++nt) {
    const int n0 = wv * 192 + nt * 16;
    const f16* Bp = Wih + (size_t)(n0 + lm) * KK + q * 8;
    f32x4 acc[4];
#pragma unroll
    for (int j = 0; j < 4; ++j) acc[j] = f32x4{0.f, 0.f, 0.f, 0.f};
#pragma unroll
    for (int k0 = 0; k0 < KK; k0 += 32) {
      f16x8 bv = *(const f16x8*)(Bp + k0);
#pragma unroll
      for (int j = 0; j < 4; ++j) {
        f16x8 av;
        if constexpr (KK == 32) {
          av = cvt8((const float*)Asrc + arow0 + (size_t)(j * 16 + lm) * KK + k0 + q * 8);
        } else {
          av = *(const f16x8*)((const f16*)Asrc + arow0 + (size_t)(j * 16 + lm) * KK + k0 + q * 8);
        }
        acc[j] = __builtin_amdgcn_mfma_f32_16x16x32_f16(av, bv, acc[j], 0, 0, 0);
      }
    }
    const float bb = biasc[n0 + lm];
#pragma unroll
    for (int j = 0; j < 4; ++j)
#pragma unroll
      for (int r = 0; r < 4; ++r)   // D: col=lane&15 (n), row=q*4+r (m)
        xp[(orow0 + j * 16 + q * 4 + r) * G3_ + n0 + lm] =
            __builtin_bit_cast(u16, (f16)(acc[j][r] + bb));
  }
}

// ---------------- pure-VALU recurrence kernel (512 thr) ---------------------
// One WG (512 thr, 8 waves) per batch row; tl_rows steps from f32 hstate.
// Thread (p=tid>>1, kh=tid&1) owns W_hh rows {p,256+p,512+p}, k-slice
// [kh*128, kh*128+128) -> w[48] uint4 = 192 VGPRs of packed fp16.
// Why 512 threads: at 8 waves/WG the per-wave budget is 512/2 = 256 VGPRs
// (__launch_bounds__(512,2) declares 2 waves/EU) -> w + working set (~227)
// fits entirely in ARCH VGPRs. At 1024 thr the budget is 128 and the
// allocator halves arch to 64 (accum_offset), pushing w into AGPRs with a
// v_accvgpr_read per use (round-5: 2.6x VALU inflation). No MFMA here ->
// no AGPR reservation at all.
template <int LAYER>
__global__ __launch_bounds__(512, 2) void gru_rec(
    const u16* __restrict__ xp,      // chunk-local [B*tl_rows][768] f16
    const f16* __restrict__ Whh16,   // f16 [768][256]
    const float* __restrict__ bhh,   // [768] (n-gate slice used)
    float* __restrict__ hstate,      // f32 [B][256], in+out across chunks
    f16* __restrict__ h1c,           // chunk-local [B*tl_rows][256] (LAYER==0)
    int tl_rows, int first) {
  const int b   = blockIdx.x;
  const int tid = threadIdx.x;
  const int p = tid >> 1, kh = tid & 1;

  // ---- W_hh -> registers (once): w[48] uint4 = 192 VGPRs ----
  uint4 w[48];
  const uint4* wsrc = (const uint4*)Whh16 + (size_t)p * 32 + kh * 16;
#pragma unroll
  for (int g = 0; g < 3; ++g)
#pragma unroll
    for (int u = 0; u < 16; ++u)
      w[g * 16 + u] = wsrc[g * 8192 + u];   // gate stride: 256 rows * 32 uint4
  const float bhn = bhh[512 + p];

  __shared__ u16 xbuf[2][TC_ * G3_];        // 98,304 B
  __shared__ __align__(16) u16 hbuf[2][H_]; // 1,024 B  (fp16 h, double-buffered)
  __shared__ u16 hhist[TC_ * H_];           // 16,384 B

  float h = first ? 0.f : hstate[b * H_ + p];
  if (kh == 0) hbuf[0][p] = __builtin_bit_cast(u16, (f16)h);
  int cur = 0;
  const uint4* xsrc = (const uint4*)xp + (size_t)b * tl_rows * 96;  // 96 uint4/row
  const int nsub = tl_rows >> 5;

#pragma unroll 1
  for (int c2 = 0; c2 < nsub; ++c2) {
    // ---- stage sub-chunk: 48KB = 3072 uint4, 6 per thread ----
    {
      const uint4* src = xsrc + (size_t)c2 * 3072;
      uint4 v0 = src[tid],        v1 = src[512 + tid],  v2 = src[1024 + tid];
      uint4 v3 = src[1536 + tid], v4 = src[2048 + tid], v5 = src[2560 + tid];
      uint4* dst = (uint4*)xbuf[c2 & 1];
      dst[tid] = v0;        dst[512 + tid] = v1;  dst[1024 + tid] = v2;
      dst[1536 + tid] = v3; dst[2048 + tid] = v4; dst[2560 + tid] = v5;
    }
    __syncthreads();   // also covers hbuf[0] init before the first step
    const u16* xrow0 = xbuf[c2 & 1];

#pragma unroll 1
    for (int tl = 0; tl < TC_; ++tl) {
      const uint4* hb = (const uint4*)(hbuf[cur] + kh * 128);  // 16 uint4, broadcast
      float ar = 0.f, az = 0.f, an = 0.f, ar2 = 0.f, az2 = 0.f, an2 = 0.f;
#pragma unroll
      for (int cc = 0; cc < 16; ++cc) {
        uint4 hv = hb[cc];
        uint4 w0 = w[cc], w1 = w[16 + cc], w2 = w[32 + cc];
        ar  = fdot2(bc2(w0.x), bc2(hv.x), ar);
        az  = fdot2(bc2(w1.x), bc2(hv.x), az);
        an  = fdot2(bc2(w2.x), bc2(hv.x), an);
        ar2 = fdot2(bc2(w0.y), bc2(hv.y), ar2);
        az2 = fdot2(bc2(w1.y), bc2(hv.y), az2);
        an2 = fdot2(bc2(w2.y), bc2(hv.y), an2);
        ar  = fdot2(bc2(w0.z), bc2(hv.z), ar);
        az  = fdot2(bc2(w1.z), bc2(hv.z), az);
        an  = fdot2(bc2(w2.z), bc2(hv.z), an);
        ar2 = fdot2(bc2(w0.w), bc2(hv.w), ar2);
        az2 = fdot2(bc2(w1.w), bc2(hv.w), az2);
        an2 = fdot2(bc2(w2.w), bc2(hv.w), an2);
      }
      ar += ar2; az += az2; an += an2;
      ar += __shfl_xor(ar, 1);
      az += __shfl_xor(az, 1);
      an += __shfl_xor(an, 1);

      const u16* xrow = xrow0 + tl * G3_;
      float xr = (float)__builtin_bit_cast(f16, xrow[p]);
      float xz = (float)__builtin_bit_cast(f16, xrow[256 + p]);
      float xn = (float)__builtin_bit_cast(f16, xrow[512 + p]);
      float r = sigm(xr + ar);                 // bhh_r folded into xp
      float z = sigm(xz + az);                 // bhh_z folded into xp
      float n = tanh_fast(xn + r * (an + bhn));
      h = n + z * (h - n);

      if (kh == 0) {
        u16 h16v = __builtin_bit_cast(u16, (f16)h);
        hbuf[cur ^ 1][p] = h16v;
        if constexpr (LAYER == 0) hhist[tl * H_ + p] = h16v;
      }
      __syncthreads();   // step-t reads done AND step-t writes visible
      cur ^= 1;
    }

    if constexpr (LAYER == 0) {
      // coalesced sub-chunk flush: 16KB, two uint4 per thread.
      // (next stage's __syncthreads orders these reads vs. hhist rewrite)
      uint4 hv0 = ((const uint4*)hhist)[tid];
      uint4 hv1 = ((const uint4*)hhist)[512 + tid];
      uint4* dst = (uint4*)(h1c + ((size_t)b * tl_rows + c2 * TC_) * H_);
      dst[tid] = hv0;
      dst[512 + tid] = hv1;
    }
  }
  if (kh == 0) hstate[b * H_ + p] = h;
}

// ---------------- projection + 96-step rollout ------------------------------
__global__ __launch_bounds__(128) void proj_rollout(
    const float* __restrict__ hfinal, const float* __restrict__ Wp,
    const float* __restrict__ bp, const float* __restrict__ Cm,
    const float* __restrict__ rld, const float* __restrict__ rtd,
    const float* __restrict__ rg, const float* __restrict__ om,
    float* __restrict__ out) {
  const int b = blockIdx.x, tid = threadIdx.x;
  __shared__ float fh[256];
  __shared__ float sb[128];
  ((float2*)fh)[tid] = ((const float2*)(hfinal + b * 256))[tid];
  __syncthreads();
  const float4* wrow = (const float4*)(Wp + tid * 256);
  float acc = 0.f;
#pragma unroll 16
  for (int k4 = 0; k4 < 64; k4++) {
    float4 wv = wrow[k4];
    acc += wv.x * fh[4 * k4] + wv.y * fh[4 * k4 + 1] + wv.z * fh[4 * k4 + 2] +
           wv.w * fh[4 * k4 + 3];
  }
  sb[tid] = acc + bp[tid];
  __syncthreads();
  if (tid < 32) {
    const int dd = tid;
    float s0 = sb[dd * 4], s1 = sb[dd * 4 + 1], s2 = sb[dd * 4 + 2], s3 = sb[dd * 4 + 3];
    float al = sigm(rld[dd]) * 0.15f + 0.85f;
    float at = sigm(rtd[dd]) * 0.25f + 0.70f;
    float g  = sigm(rg[dd]) * 0.20f + 0.80f;
    float cw = cosf(om[dd]), sw = sinf(om[dd]);
    float r00 = g * cw, r01 = -g * sw, r10 = g * sw, r11 = g * cw;
    float c0 = Cm[dd * 4], c1 = Cm[dd * 4 + 1], c2 = Cm[dd * 4 + 2], c3 = Cm[dd * 4 + 3];
    float* op = out + (size_t)b * PRED_ * D_ + dd;
    for (int t = 0; t < PRED_; t++) {
      float n0 = s0 * al, n1 = s1 * at;
      float n2 = s2 * r00 + s3 * r10;
      float n3 = s2 * r01 + s3 * r11;
      op[(size_t)t * D_] = c0 * n0 + c1 * n1 + c2 * n2 + c3 * n3;
      s0 = n0; s1 = n1; s2 = n2; s3 = n3;
    }
  }
}

extern "C" void kernel_launch(void* const* d_in, const int* in_sizes, int n_in,
                              void* d_out, int out_size, void* d_ws,
                              size_t ws_size, hipStream_t stream) {
  (void)in_sizes; (void)n_in; (void)out_size;
  const float* x     = (const float*)d_in[0];
  const float* Wih0  = (const float*)d_in[1];
  const float* Whh0  = (const float*)d_in[2];
  const float* bih0  = (const float*)d_in[3];
  const float* bhh0  = (const float*)d_in[4];
  const float* Wih1  = (const float*)d_in[5];
  const float* Whh1  = (const float*)d_in[6];
  const float* bih1  = (const float*)d_in[7];
  const float* bhh1  = (const float*)d_in[8];
  const float* Wproj = (const float*)d_in[9];
  const float* bproj = (const float*)d_in[10];
  const float* Cm    = (const float*)d_in[11];
  const float* rld   = (const float*)d_in[12];
  const float* rtd   = (const float*)d_in[13];
  const float* rg    = (const float*)d_in[14];
  const float* om    = (const float*)d_in[15];
  float* out = (float*)d_out;

  char* ws = (char*)d_ws;
  // fixed region
  const size_t wi0_off  = 0;           //    49,152
  const size_t wi1_off  = 49152;       //   393,216
  const size_t whh0_off = 442368;      //   393,216
  const size_t whh1_off = 835584;      //   393,216
  const size_t b0_off   = 1228800;     //     3,072
  const size_t b1_off   = 1231872;     //     3,072
  const size_t hs0_off  = 1234944;     //   262,144 (f32 [B][256])
  const size_t hs1_off  = 1497088;     //   262,144
  const size_t h1c_off  = 1759232;     // h1 chunk: B*TL*256*2
  // xpc follows h1c; sizes depend on TL.
  const size_t need64  = h1c_off + (size_t)B_ * 64 * H_ * 2  + (size_t)B_ * 64 * G3_ * 2;   // 35,313,664
  const size_t need128 = h1c_off + (size_t)B_ * 128 * H_ * 2 + (size_t)B_ * 128 * G3_ * 2;  // 68,868,096

  if (ws_size < need64) {
    fprintf(stderr, "kernel_launch: ws too small: have %zu need %zu — skipping\n",
            ws_size, need64);
    return;
  }
  const int TL = (ws_size >= need128) ? 128 : 64;
  const size_t xpc_off = h1c_off + (size_t)B_ * TL * H_ * 2;

  f16* wi016   = (f16*)(ws + wi0_off);
  f16* wi116   = (f16*)(ws + wi1_off);
  f16* whh016  = (f16*)(ws + whh0_off);
  f16* whh116  = (f16*)(ws + whh1_off);
  float* bias0 = (float*)(ws + b0_off);
  float* bias1 = (float*)(ws + b1_off);
  float* hst0  = (float*)(ws + hs0_off);
  float* hst1  = (float*)(ws + hs1_off);
  f16* h1c     = (f16*)(ws + h1c_off);
  u16* xpc     = (u16*)(ws + xpc_off);

  f32_to_f16_k<<<96, 256, 0, stream>>>(Wih0, wi016, G3_ * IN_);
  f32_to_f16_k<<<768, 256, 0, stream>>>(Wih1, wi116, G3_ * H_);
  f32_to_f16_k<<<768, 256, 0, stream>>>(Whh0, whh016, G3_ * H_);
  f32_to_f16_k<<<768, 256, 0, stream>>>(Whh1, whh116, G3_ * H_);
  make_bias<<<3, 256, 0, stream>>>(bih0, bhh0, bias0);
  make_bias<<<3, 256, 0, stream>>>(bih1, bhh1, bias1);

  const int nchunks = S_ / TL;
  const int gblocks = B_ * (TL / 64);
  for (int c = 0; c < nchunks; ++c) {
    gemm_xp<IN_><<<gblocks, 256, 0, stream>>>(
        (const void*)(x + (size_t)c * TL * IN_), (size_t)S_ * IN_, TL, wi016, bias0, xpc);
    gru_rec<0><<<B_, 512, 0, stream>>>(xpc, whh016, bhh0, hst0, h1c, TL, c == 0);
    gemm_xp<H_><<<gblocks, 256, 0, stream>>>(
        (const void*)h1c, (size_t)TL * H_, TL, wi116, bias1, xpc);
    gru_rec<1><<<B_, 512, 0, stream>>>(xpc, whh116, bhh1, hst1, nullptr, TL, c == 0);
  }
  proj_rollout<<<B_, 128, 0, stream>>>(hst1, Wproj, bproj, Cm, rld, rtd, rg, om, out);
}